// Round 20
// baseline (320.140 us; speedup 1.0000x reference)
//
#include <hip/hip_runtime.h>

#define LN 63
#define BATCHN 16384

typedef __attribute__((ext_vector_type(8))) short bf16x8;   // 8 bf16 in 4 VGPRs
typedef __attribute__((ext_vector_type(4))) float f32x4;

__device__ __forceinline__ float fast_exp(float v) {
    return __builtin_amdgcn_exp2f(v * 1.4426950408889634f);
}
__device__ __forceinline__ float fast_tanh(float v) {
    float e = __builtin_amdgcn_exp2f(v * 2.8853900817779268f); // e^{2v}
    return 1.0f - 2.0f * __builtin_amdgcn_rcpf(e + 1.0f);
}
__device__ __forceinline__ short f2bf(float f) {
    __bf16 h = (__bf16)f;
    return __builtin_bit_cast(short, h);
}
__device__ __forceinline__ unsigned int pk2(float a, float b) {
    return (unsigned int)(unsigned short)f2bf(a) |
           ((unsigned int)(unsigned short)f2bf(b) << 16);
}

// kappa j-index for W2/W3 fragment element e (derived from R6's verified LDS
// reads): e<4 -> 32s+4g+e ; e>=4 -> 32s+16+4g+(e-4).
__device__ __forceinline__ int kappa_j(int s, int g, int e) {
    return (e < 4) ? (32 * s + 4 * g + e) : (32 * s + 16 + 4 * g + e - 4);
}

// Combined prep: blocks 0..62 write per-lane fragment-ordered bf16 weights
// into Afrag[l] (18432 B per l); blocks 63.. convert x -> xbf.  (R9-verified)
__global__ __launch_bounds__(256) void prep_kernel(
    const float* __restrict__ x,
    const float* __restrict__ W1, const float* __restrict__ b1,
    const float* __restrict__ W2, const float* __restrict__ W3,
    unsigned short* __restrict__ Afrag,
    unsigned short* __restrict__ xbf)
{
    const int t = threadIdx.x;
    const int b = blockIdx.x;
    if (b >= LN) {
        const int i = ((b - LN) * 256 + t) * 4;
        const float4 v = *reinterpret_cast<const float4*>(x + i);
        ushort4 o;
        o.x = (unsigned short)f2bf(v.x);
        o.y = (unsigned short)f2bf(v.y);
        o.z = (unsigned short)f2bf(v.z);
        o.w = (unsigned short)f2bf(v.w);
        *reinterpret_cast<ushort4*>(xbf + i) = o;
        return;
    }
    const int l = b;
    unsigned short* Af = Afrag + (size_t)l * 9216;

    // A1: 512 items (s,tt,lane), 2 per thread
    #pragma unroll
    for (int it = 0; it < 2; ++it) {
        const int item = t + it * 256;
        const int s = item >> 8, tt = (item >> 6) & 3, lane = item & 63;
        const int g = lane >> 4, mcol = lane & 15, h = 16 * tt + mcol;
        unsigned pk[4];
        #pragma unroll
        for (int ep = 0; ep < 4; ++ep) {
            float v[2];
            #pragma unroll
            for (int k = 0; k < 2; ++k) {
                const int e = 2 * ep + k;
                const int j = 32 * s + 8 * g + e;
                float val;
                if (j == 63)      val = b1[l * 64 + h];
                else if (j <= l)  val = W1[(l * LN + j) * 64 + h];
                else              val = 0.0f;
                v[k] = val;
            }
            pk[ep] = pk2(v[0], v[1]);
        }
        *reinterpret_cast<uint4*>(Af + ((size_t)item) * 8) =
            uint4{pk[0], pk[1], pk[2], pk[3]};
    }
    // A2: 512 items
    #pragma unroll
    for (int it = 0; it < 2; ++it) {
        const int item = t + it * 256;
        const int s = item >> 8, tt = (item >> 6) & 3, lane = item & 63;
        const int g = lane >> 4, mcol = lane & 15, h = 16 * tt + mcol;
        unsigned pk[4];
        #pragma unroll
        for (int ep = 0; ep < 4; ++ep) {
            float v[2];
            #pragma unroll
            for (int k = 0; k < 2; ++k) {
                const int e = 2 * ep + k;
                v[k] = W2[(l * 64 + kappa_j(s, g, e)) * 64 + h];
            }
            pk[ep] = pk2(v[0], v[1]);
        }
        *reinterpret_cast<uint4*>(Af + 4096 + ((size_t)item) * 8) =
            uint4{pk[0], pk[1], pk[2], pk[3]};
    }
    // A3: 128 items (s,lane)
    if (t < 128) {
        const int s = t >> 6, lane = t & 63;
        const int g = lane >> 4, mcol = lane & 15;
        unsigned pk[4] = {0u, 0u, 0u, 0u};
        if (mcol < 2) {
            #pragma unroll
            for (int ep = 0; ep < 4; ++ep) {
                float v[2];
                #pragma unroll
                for (int k = 0; k < 2; ++k) {
                    const int e = 2 * ep + k;
                    v[k] = W3[(l * 64 + kappa_j(s, g, e)) * 2 + mcol];
                }
                pk[ep] = pk2(v[0], v[1]);
            }
        }
        *reinterpret_cast<uint4*>(Af + 8192 + ((size_t)t) * 8) =
            uint4{pk[0], pk[1], pk[2], pk[3]};
    }
}

// Block = one l (0..62) x 1024 batch rows (rowTile 0..15). Grid 63*16 = 1008.
// Body = R15 (verified absmax 0.0625, 48.2us floor). R19: the separate finish
// kernel is FOLDED IN via device-scope producer-consumer handshake: after its
// grp loop each block does threadfence+atomicAdd(cnt[rowTile]); the 63rd
// arrival runs the finish phase (log_det + z transpose) for its 1024 rows.
// Deterministic: cnt zeroed per launch; consumer reads only fully-written
// zT/aT; summation order fixed regardless of which block consumes.
__global__ __launch_bounds__(256) void maf_main_kernel(
    const float* __restrict__ x,
    const float* __restrict__ ip,
    const unsigned short* __restrict__ xbf,
    const unsigned short* __restrict__ Afrag,
    const float* __restrict__ b2,
    const float* __restrict__ b3,
    float* zT,                // ws: [63][BATCH] row cr=62-l (z col l+1 reversed)
    float* aT,                // ws: [63][BATCH] alpha col l+1
    int* cnt,                 // ws: [16] arrival counters (zeroed per launch)
    float* __restrict__ z_out,
    float* __restrict__ ld_out)
{
    __shared__ float tile[64][65];   // used only in the finish phase
    __shared__ int s_last;

    const int t = threadIdx.x;
    const int bid = blockIdx.x;
    const int l = bid % LN;                 // block-uniform
    const int rowTile = bid / LN;           // 0..15
    const int rowBase = rowTile * 1024;

    const int lane = t & 63;
    const int w = t >> 6;
    const int g = lane >> 4;
    const int mcol = lane & 15;

    const unsigned short* Af = Afrag + (size_t)l * 9216;
    const unsigned short* Af1 = Af + lane * 8;           // w1f base (per-lane)
    const unsigned short* Af2 = Af + 4096 + lane * 8;    // w2f base
    const unsigned short* Af3 = Af + 8192 + lane * 8;    // w3f base

    f32x4 bias2[4];
    #pragma unroll
    for (int tt = 0; tt < 4; ++tt) {
        const float4 v2 = *reinterpret_cast<const float4*>(&b2[l * 64 + 16 * tt + 4 * g]);
        bias2[tt] = f32x4{v2.x, v2.y, v2.z, v2.w};
    }
    const float b30 = b3[l * 2 + 0];
    const float b31 = b3[l * 2 + 1];
    const short one_bf = (short)0x3F80;   // bf16(1.0)

    const int rowW = rowBase + w * 256 + mcol;
    const unsigned short* xrow = xbf + (size_t)rowW * 64 + 8 * g;

    // ---------------- 16 groups of 16 rows per wave ----------------
    #pragma unroll 1
    for (int grp = 0; grp < 16; ++grp) {
        const unsigned short* xp = xrow + (size_t)(16 * grp) * 64;

        bf16x8 xf0 = *reinterpret_cast<const bf16x8*>(xp);
        bf16x8 xf1 = *reinterpret_cast<const bf16x8*>(xp + 32);
        if (g == 3) xf1[7] = one_bf;   // b1 k-slot 63 pairs with 1.0

        // ---- layer 1: w1f loaded fresh (L1-hot) ----
        f32x4 c1[4];
        #pragma unroll
        for (int tt = 0; tt < 4; ++tt) {
            const bf16x8 wa = *reinterpret_cast<const bf16x8*>(Af1 + (0 * 4 + tt) * 512);
            c1[tt] = __builtin_amdgcn_mfma_f32_16x16x32_bf16(
                wa, xf0, f32x4{0.0f, 0.0f, 0.0f, 0.0f}, 0, 0, 0);
        }
        #pragma unroll
        for (int tt = 0; tt < 4; ++tt) {
            const bf16x8 wa = *reinterpret_cast<const bf16x8*>(Af1 + (1 * 4 + tt) * 512);
            c1[tt] = __builtin_amdgcn_mfma_f32_16x16x32_bf16(wa, xf1, c1[tt], 0, 0, 0);
        }

        // ---- tanh + pack ----
        bf16x8 pf0, pf1;
        #pragma unroll
        for (int q = 0; q < 4; ++q) {
            pf0[q]     = f2bf(fast_tanh(c1[0][q]));
            pf0[4 + q] = f2bf(fast_tanh(c1[1][q]));
            pf1[q]     = f2bf(fast_tanh(c1[2][q]));
            pf1[4 + q] = f2bf(fast_tanh(c1[3][q]));
        }

        // ---- layer 2: w2f loaded fresh ----
        f32x4 c2[4];
        #pragma unroll
        for (int tt = 0; tt < 4; ++tt) {
            const bf16x8 wa = *reinterpret_cast<const bf16x8*>(Af2 + (0 * 4 + tt) * 512);
            c2[tt] = __builtin_amdgcn_mfma_f32_16x16x32_bf16(wa, pf0, bias2[tt], 0, 0, 0);
        }
        #pragma unroll
        for (int tt = 0; tt < 4; ++tt) {
            const bf16x8 wa = *reinterpret_cast<const bf16x8*>(Af2 + (1 * 4 + tt) * 512);
            c2[tt] = __builtin_amdgcn_mfma_f32_16x16x32_bf16(wa, pf1, c2[tt], 0, 0, 0);
        }

        bf16x8 qf0, qf1;
        #pragma unroll
        for (int q = 0; q < 4; ++q) {
            qf0[q]     = f2bf(fast_tanh(c2[0][q]));
            qf0[4 + q] = f2bf(fast_tanh(c2[1][q]));
            qf1[q]     = f2bf(fast_tanh(c2[2][q]));
            qf1[4 + q] = f2bf(fast_tanh(c2[3][q]));
        }

        // ---- layer 3: w3f loaded fresh ----
        const bf16x8 w30 = *reinterpret_cast<const bf16x8*>(Af3);
        const bf16x8 w31 = *reinterpret_cast<const bf16x8*>(Af3 + 512);
        f32x4 c3 = {0.0f, 0.0f, 0.0f, 0.0f};
        c3 = __builtin_amdgcn_mfma_f32_16x16x32_bf16(w30, qf0, c3, 0, 0, 0);
        c3 = __builtin_amdgcn_mfma_f32_16x16x32_bf16(w31, qf1, c3, 0, 0, 0);

        if (g == 0) {
            const int row = rowW + 16 * grp;
            const float mu = c3[0] + b30;
            const float al = c3[1] + b31;
            const float xn = x[(size_t)row * 64 + l + 1];   // f32 input
            const float zv = (xn - mu) * fast_exp(-al);
            zT[(62 - l) * BATCHN + row] = zv;
            aT[l * BATCHN + row] = al;
        }
    }

    // ---------------- handshake: last l-block of this rowTile finishes ------
    __threadfence();                       // release: publish zT/aT writes
    if (t == 0) {
        const int old = atomicAdd(&cnt[rowTile], 1);
        s_last = (old == LN - 1) ? 1 : 0;
    }
    __syncthreads();
    if (!s_last) return;
    __threadfence();                       // acquire: see all blocks' writes

    // ---------------- finish phase: 16 chunks of 64 rows ----------------
    const float mu0 = ip[0];
    const float a0  = ip[1];
    const float e0  = fast_exp(-a0);

    #pragma unroll 1
    for (int ch = 0; ch < 16; ++ch) {
        const int rb = rowBase + ch * 64;

        // log_det: 4 lanes per row, shfl reduce
        {
            const int r = t >> 2, c = t & 3;
            const int row = rb + r;
            float s = 0.0f;
            for (int i = c; i < LN; i += 4) s += aT[(size_t)i * BATCHN + row];
            s += __shfl_xor(s, 1, 64);
            s += __shfl_xor(s, 2, 64);
            if (c == 0) ld_out[row] = -(s + a0);
        }

        // transpose 64 rows x 64 cols
        const int r2 = t & 63, cq = t >> 6;
        #pragma unroll
        for (int k = 0; k < 16; ++k) {
            const int c = cq * 16 + k;
            float v;
            if (c < 63) v = zT[(size_t)c * BATCHN + rb + r2];
            else        v = (x[(size_t)(rb + r2) * 64] - mu0) * e0;  // z col 0
            tile[c][r2] = v;
        }
        __syncthreads();
        #pragma unroll
        for (int i = 0; i < 16; ++i) {
            const int rr = cq * 16 + i;
            z_out[(size_t)(rb + rr) * 64 + r2] = tile[r2][rr];
        }
        __syncthreads();
    }
}

extern "C" void kernel_launch(void* const* d_in, const int* in_sizes, int n_in,
                              void* d_out, int out_size, void* d_ws, size_t ws_size,
                              hipStream_t stream) {
    const float* x  = (const float*)d_in[0];
    const float* ip = (const float*)d_in[1];
    const float* W1 = (const float*)d_in[2];
    const float* b1 = (const float*)d_in[3];
    const float* W2 = (const float*)d_in[4];
    const float* b2 = (const float*)d_in[5];
    const float* W3 = (const float*)d_in[6];
    const float* b3 = (const float*)d_in[7];

    float* z_out  = (float*)d_out;                     // [16384][64] (reversed cols)
    float* ld_out = z_out + (size_t)BATCHN * 64;       // [16384]

    // ws: Afrag 1.11MB | zT 4.13MB | aT 4.13MB | xbf 2MB | cnt 64B
    unsigned short* Afrag = (unsigned short*)d_ws;
    float* zT = (float*)((char*)d_ws + (size_t)LN * 9216 * 2);
    float* aT = zT + (size_t)LN * BATCHN;
    unsigned short* xbf = (unsigned short*)(aT + (size_t)LN * BATCHN);
    int* cnt = (int*)(xbf + (size_t)BATCHN * 64);

    hipMemsetAsync(cnt, 0, 16 * sizeof(int), stream);
    prep_kernel<<<dim3(LN + BATCHN * 64 / 1024), dim3(256), 0, stream>>>(
        x, W1, b1, W2, W3, Afrag, xbf);
    maf_main_kernel<<<dim3(LN * 16), dim3(256), 0, stream>>>(
        x, ip, xbf, Afrag, b2, b3, zT, aT, cnt, z_out, ld_out);
}